// Round 2
// baseline (1090.263 us; speedup 1.0000x reference)
//
#include <hip/hip_runtime.h>
#include <math.h>

#define T_STEPS 256
#define BATCH   4096
#define HID     64
#define MW      128
#define DOUT    8
#define RPB     8     // live batch rows per block (grid = 512 -> 2 blocks/CU)
#define MROWS   16    // MFMA M-tile rows in LDS (rows RPB..15 are dead padding)
#define NTH     512   // 8 waves: (mlp 2) x (neuron-quarter 4)
#define NW      8
#define AS      72    // Ain/zb row stride in halfs (144B: 16B-aligned, 2-way banks)
#define HS      136   // h1/h2 row stride in halfs (272B: 16B-aligned, 2-way banks)

typedef _Float16 half8 __attribute__((ext_vector_type(8)));
typedef float    f32x4 __attribute__((ext_vector_type(4)));

__device__ __forceinline__ float fast_rcp(float x) { return __builtin_amdgcn_rcpf(x); }
__device__ __forceinline__ float lipswish(float x) {
    float e = __expf(-x);
    return 0.909f * x * fast_rcp(1.0f + e);
}
__device__ __forceinline__ float fast_tanh(float x) {
    float e = __expf(2.0f * x);
    return 1.0f - 2.0f * fast_rcp(e + 1.0f);
}

#define MFMA(a, b, c) __builtin_amdgcn_mfma_f32_16x16x32_f16((a), (b), (c), 0, 0, 0)

// MFMA 16x16x32 layout conventions (gfx950, guide-verified):
//   A[m][k]: m = lane&15, k = (lane>>4)*8 + j   (8 halfs, K-contiguous)
//   B[k][n]: n = lane&15, k = (lane>>4)*8 + j
//   C/D   : col n = lane&15, row m = (lane>>4)*4 + reg
// Output row m depends only on A row m, so garbage in pad rows 8..15
// never contaminates live rows 0..7.

__global__ __launch_bounds__(NTH, 4)
void sde_kernel(const float* __restrict__ ts,
                const float* __restrict__ dW,
                const float* __restrict__ dW0, const float* __restrict__ db0,
                const float* __restrict__ dW1, const float* __restrict__ db1,
                const float* __restrict__ dWo, const float* __restrict__ dbo,
                const float* __restrict__ gW0, const float* __restrict__ gb0,
                const float* __restrict__ gW1, const float* __restrict__ gb1,
                const float* __restrict__ gWo, const float* __restrict__ gbo,
                const float* __restrict__ rW,  const float* __restrict__ rb,
                float* __restrict__ out)
{
    __shared__ _Float16 Ain_hi[MROWS][AS];   // L1 input (t-folded), hi part
    __shared__ _Float16 Ain_lo[MROWS][AS];   // L1 input, lo part (fp32-exact split)
    __shared__ _Float16 h1b[2][MROWS][HS];   // layer-1 out per mlp
    __shared__ _Float16 h2b[2][MROWS][HS];   // layer-2 out per mlp
    __shared__ _Float16 zb[2][MROWS][AS];    // z stash (f16) for MFMA readout
    __shared__ _Float16 fgb[2][MROWS][HID];  // [0]=f, [1]=g
    __shared__ float    bias1t[2 * MW];      // per-step L1 bias incl. t * W0row0
    __shared__ float    tsS[T_STEPS];

    const int tid  = threadIdx.x;
    const int lane = tid & 63;
    const int wid  = tid >> 6;     // 0..7
    const int l15  = lane & 15;
    const int quad = lane >> 4;
    const int mlp  = wid >> 2;     // 0 = drift, 1 = diff
    const int nq   = wid & 3;      // neuron quarter (32-col slice of L1/L2, 16-col of L3)
    const int rowbase = blockIdx.x * RPB;

    for (int i = tid; i < T_STEPS; i += NTH) tsS[i] = ts[i];

    const float t0   = ts[0];
    const float dt   = ts[1] - t0;
    const float sqdt = sqrtf(dt);

    // ---------------- static weight fragments in VGPRs ----------------
    const float* W0 = mlp ? gW0 : dW0;   // (65,128); row 0 = t weights
    const float* W1 = mlp ? gW1 : dW1;   // (128,128)
    const float* Wo = mlp ? gWo : dWo;   // (128,64)

    half8 bw1[2][2], bw2[4][2], bw3[4];
    #pragma unroll
    for (int kt = 0; kt < 2; ++kt)
        #pragma unroll
        for (int nt = 0; nt < 2; ++nt) {
            half8 v;
            #pragma unroll
            for (int j = 0; j < 8; ++j) {
                const int k = kt * 32 + quad * 8 + j;
                const int n = nq * 32 + nt * 16 + l15;
                v[j] = (_Float16)W0[(1 + k) * MW + n];
            }
            bw1[kt][nt] = v;
        }
    #pragma unroll
    for (int kt = 0; kt < 4; ++kt)
        #pragma unroll
        for (int nt = 0; nt < 2; ++nt) {
            half8 v;
            #pragma unroll
            for (int j = 0; j < 8; ++j) {
                const int k = kt * 32 + quad * 8 + j;
                const int n = nq * 32 + nt * 16 + l15;
                v[j] = (_Float16)W1[k * MW + n];
            }
            bw2[kt][nt] = v;
        }
    #pragma unroll
    for (int kt = 0; kt < 4; ++kt) {
        half8 v;
        #pragma unroll
        for (int j = 0; j < 8; ++j) {
            const int k = kt * 32 + quad * 8 + j;
            const int n = nq * 16 + l15;
            v[j] = (_Float16)Wo[k * HID + n];
        }
        bw3[kt] = v;
    }

    float b2v[2], b3v;
    {
        const float* b1p = mlp ? gb1 : db1;
        const float* bop = mlp ? gbo : dbo;
        #pragma unroll
        for (int nt = 0; nt < 2; ++nt) b2v[nt] = b1p[nq * 32 + nt * 16 + l15];
        b3v = bop[nq * 16 + l15];
    }

    // readout fragments (wave 0 only)
    half8 brd[2];
    float rbv = 0.0f;
    int   ocol = 0;
    if (wid == 0) {
        #pragma unroll
        for (int kt = 0; kt < 2; ++kt) {
            half8 v;
            #pragma unroll
            for (int j = 0; j < 8; ++j) {
                const int k = kt * 32 + quad * 8 + j;
                v[j] = (l15 < 8) ? (_Float16)rW[k * DOUT + l15] : (_Float16)0.0f;
            }
            brd[kt] = v;
        }
        rbv  = (l15 < 8) ? rb[l15] : 0.0f;
        ocol = (l15 == 8) ? 0 : (l15 + 1);
    }

    // per-thread statics for the t-folded L1 bias (thread -> (mlp, neuron)), tid<256
    float b0s = 0.0f, w0s = 0.0f;
    if (tid < 2 * MW) {
        b0s = (tid < MW ? db0 : gb0)[tid & (MW - 1)];
        w0s = (tid < MW ? dW0 : gW0)[tid & (MW - 1)];  // W0 row 0
    }

    // ---------------- state registers (update mapping: dim=lane, row=wid) ----
    const int ud = lane;
    float z = 1.0f, zh = 1.0f, fold, gold, dwr = 0.0f, dn;

    // ---- pre-loop: Ain <- (x0 = ones), pad rows zeroed, bias1t(t0), prefetch dW[0] ----
    Ain_hi[wid][ud] = (_Float16)1.0f;
    Ain_lo[wid][ud] = (_Float16)0.0f;
    Ain_hi[wid + RPB][ud] = (_Float16)0.0f;
    Ain_lo[wid + RPB][ud] = (_Float16)0.0f;
    zb[0][wid][ud] = (_Float16)0.0f;
    zb[1][wid][ud] = (_Float16)0.0f;
    zb[0][wid + RPB][ud] = (_Float16)0.0f;
    zb[1][wid + RPB][ud] = (_Float16)0.0f;
    dn = dW[(size_t)(rowbase + wid) * HID + ud];
    if (tid < 2 * MW) bias1t[tid] = b0s + t0 * w0s;
    __syncthreads();

    for (int n = 1; n <= T_STEPS; ++n) {
        // ================= Layer 1: 64 -> 128 (split-A, 2 mfma/tile) ===========
        {
            const int koff = quad * 8;
            half8 ah[2], al[2];
            #pragma unroll
            for (int kt = 0; kt < 2; ++kt) {
                ah[kt] = *(const half8*)&Ain_hi[l15][kt * 32 + koff];
                al[kt] = *(const half8*)&Ain_lo[l15][kt * 32 + koff];
            }
            f32x4 acc[2];
            #pragma unroll
            for (int nt = 0; nt < 2; ++nt) {
                const float b = bias1t[mlp * MW + nq * 32 + nt * 16 + l15];
                acc[nt] = (f32x4){b, b, b, b};
            }
            #pragma unroll
            for (int nt = 0; nt < 2; ++nt)
                #pragma unroll
                for (int kt = 0; kt < 2; ++kt) {
                    acc[nt] = MFMA(ah[kt], bw1[kt][nt], acc[nt]);
                    acc[nt] = MFMA(al[kt], bw1[kt][nt], acc[nt]);
                }
            #pragma unroll
            for (int nt = 0; nt < 2; ++nt)
                #pragma unroll
                for (int i2 = 0; i2 < 4; ++i2) {
                    const float v = lipswish(acc[nt][i2]);
                    h1b[mlp][quad * 4 + i2][nq * 32 + nt * 16 + l15] = (_Float16)v;
                }

            // -------- readout of z_{n-2} via MFMA (wave 0) --------
            if (wid == 0 && n >= 2) {
                const int q = (n - 1) & 1, s = n - 2;
                half8 a0 = *(const half8*)&zb[q][l15][koff];
                half8 a1 = *(const half8*)&zb[q][l15][32 + koff];
                f32x4 racc = (f32x4){rbv, rbv, rbv, rbv};
                racc = MFMA(a0, brd[0], racc);
                racc = MFMA(a1, brd[1], racc);
                if (l15 < 9 && quad < RPB / 4) {   // only live rows 0..7
                    const float tv = tsS[s];
                    #pragma unroll
                    for (int i2 = 0; i2 < 4; ++i2) {
                        const int r = quad * 4 + i2;
                        out[(size_t)(rowbase + r) * (T_STEPS * 9) + s * 9 + ocol]
                            = (l15 < 8) ? racc[i2] : tv;
                    }
                }
            }
        }
        __syncthreads();

        // ================= Layer 2: 128 -> 128 =================
        {
            half8 a[4];
            #pragma unroll
            for (int kt = 0; kt < 4; ++kt)
                a[kt] = *(const half8*)&h1b[mlp][l15][kt * 32 + quad * 8];
            f32x4 acc[2];
            #pragma unroll
            for (int nt = 0; nt < 2; ++nt)
                acc[nt] = (f32x4){b2v[nt], b2v[nt], b2v[nt], b2v[nt]};
            #pragma unroll
            for (int nt = 0; nt < 2; ++nt)
                #pragma unroll
                for (int kt = 0; kt < 4; ++kt)
                    acc[nt] = MFMA(a[kt], bw2[kt][nt], acc[nt]);
            #pragma unroll
            for (int nt = 0; nt < 2; ++nt)
                #pragma unroll
                for (int i2 = 0; i2 < 4; ++i2) {
                    const float v = lipswish(acc[nt][i2]);
                    h2b[mlp][quad * 4 + i2][nq * 32 + nt * 16 + l15] = (_Float16)v;
                }
        }
        __syncthreads();

        // ================= Layer 3: 128 -> 64, tanh =================
        {
            half8 a[4];
            #pragma unroll
            for (int kt = 0; kt < 4; ++kt)
                a[kt] = *(const half8*)&h2b[mlp][l15][kt * 32 + quad * 8];
            f32x4 acc = (f32x4){b3v, b3v, b3v, b3v};
            #pragma unroll
            for (int kt = 0; kt < 4; ++kt)
                acc = MFMA(a[kt], bw3[kt], acc);
            #pragma unroll
            for (int i2 = 0; i2 < 4; ++i2)
                fgb[mlp][quad * 4 + i2][nq * 16 + l15]
                    = (_Float16)fast_tanh(acc[i2]);
        }
        __syncthreads();

        // ================= Update phase (one live row per wave) =================
        {
            const float fn = (float)fgb[0][wid][ud];
            const float gn = (float)fgb[1][wid][ud];
            if (n > 1)
                z += 0.5f * (fold + fn) * dt + 0.5f * (gold + gn) * dwr;
            const int p = n & 1;
            zb[p][wid][ud] = (_Float16)z;

            if (n < T_STEPS) {
                const int np = (n < T_STEPS - 2) ? n : (T_STEPS - 2);
                dwr = dn * sqdt;
                dn  = dW[(size_t)np * (BATCH * HID) + (size_t)(rowbase + wid) * HID + ud];
                zh  = 2.0f * z - zh + fn * dt + gn * dwr;
                const _Float16 hi = (_Float16)zh;
                Ain_hi[wid][ud] = hi;
                Ain_lo[wid][ud] = (_Float16)(zh - (float)hi);
                if (tid < 2 * MW) bias1t[tid] = b0s + tsS[n] * w0s;
            }
            fold = fn; gold = gn;
        }
        __syncthreads();
    }

    // ---- epilogue: readout of z_255 (stashed in zb[0] at U(256)) ----
    if (wid == 0) {
        const int koff = quad * 8, s = T_STEPS - 1;
        half8 a0 = *(const half8*)&zb[0][l15][koff];
        half8 a1 = *(const half8*)&zb[0][l15][32 + koff];
        f32x4 racc = (f32x4){rbv, rbv, rbv, rbv};
        racc = MFMA(a0, brd[0], racc);
        racc = MFMA(a1, brd[1], racc);
        if (l15 < 9 && quad < RPB / 4) {
            const float tv = tsS[s];
            #pragma unroll
            for (int i2 = 0; i2 < 4; ++i2) {
                const int r = quad * 4 + i2;
                out[(size_t)(rowbase + r) * (T_STEPS * 9) + s * 9 + ocol]
                    = (l15 < 8) ? racc[i2] : tv;
            }
        }
    }
}

extern "C" void kernel_launch(void* const* d_in, const int* in_sizes, int n_in,
                              void* d_out, int out_size, void* d_ws, size_t ws_size,
                              hipStream_t stream) {
    const float* ts  = (const float*)d_in[0];
    const float* dW  = (const float*)d_in[2];
    const float* dW0 = (const float*)d_in[3];
    const float* db0 = (const float*)d_in[4];
    const float* dW1 = (const float*)d_in[5];
    const float* db1 = (const float*)d_in[6];
    const float* dWo = (const float*)d_in[7];
    const float* dbo = (const float*)d_in[8];
    const float* gW0 = (const float*)d_in[9];
    const float* gb0 = (const float*)d_in[10];
    const float* gW1 = (const float*)d_in[11];
    const float* gb1 = (const float*)d_in[12];
    const float* gWo = (const float*)d_in[13];
    const float* gbo = (const float*)d_in[14];
    const float* rW  = (const float*)d_in[15];
    const float* rb  = (const float*)d_in[16];
    float* out = (float*)d_out;

    sde_kernel<<<dim3(BATCH / RPB), dim3(NTH), 0, stream>>>(
        ts, dW, dW0, db0, dW1, db1, dWo, dbo,
        gW0, gb0, gW1, gb1, gWo, gbo, rW, rb, out);
}

// Round 3
// 681.884 us; speedup vs baseline: 1.5989x; 1.5989x over previous
//
#include <hip/hip_runtime.h>
#include <math.h>

#define T_STEPS 256
#define BATCH   4096
#define HID     64
#define MW      128
#define DOUT    8
#define RPB     16    // rows per block -> grid = 256 = 1 block/CU (grid-limited)
#define NTH     512   // 8 waves: phase1/2: (mlp 2) x (neuron-quarter 4)
#define AS      72    // Ain/zb row stride in halfs (144B: 16B-aligned, 2-way banks)
#define HS      136   // h1/h2 row stride in halfs (272B: 16B-aligned, 2-way banks)

typedef _Float16 half8 __attribute__((ext_vector_type(8)));
typedef float    f32x4 __attribute__((ext_vector_type(4)));

__device__ __forceinline__ float fast_rcp(float x) { return __builtin_amdgcn_rcpf(x); }
__device__ __forceinline__ float lipswish(float x) {
    float e = __expf(-x);
    return 0.909f * x * fast_rcp(1.0f + e);
}
__device__ __forceinline__ float fast_tanh(float x) {
    float e = __expf(2.0f * x);
    return 1.0f - 2.0f * fast_rcp(e + 1.0f);
}

#define MFMA(a, b, c) __builtin_amdgcn_mfma_f32_16x16x32_f16((a), (b), (c), 0, 0, 0)

// MFMA 16x16x32 layout (gfx950, guide-verified):
//   A[m][k]: m = lane&15, k = (lane>>4)*8 + j
//   B[k][n]: n = lane&15, k = (lane>>4)*8 + j
//   C/D   : col n = lane&15, row m = (lane>>4)*4 + reg
// Phase 3 exploits C/D layout directly: the lane that produces f,g for
// (rows quad*4+i, col nq*16+l15) also owns z/zhat state for those elements,
// so the update needs no cross-lane/LDS transpose (fgb eliminated, 3 barriers).

__global__ __launch_bounds__(NTH, 1)   // grid=1 block/CU: VGPRs free up to ~170
void sde_kernel(const float* __restrict__ ts,
                const float* __restrict__ dW,
                const float* __restrict__ dW0, const float* __restrict__ db0,
                const float* __restrict__ dW1, const float* __restrict__ db1,
                const float* __restrict__ dWo, const float* __restrict__ dbo,
                const float* __restrict__ gW0, const float* __restrict__ gb0,
                const float* __restrict__ gW1, const float* __restrict__ gb1,
                const float* __restrict__ gWo, const float* __restrict__ gbo,
                const float* __restrict__ rW,  const float* __restrict__ rb,
                float* __restrict__ out)
{
    __shared__ _Float16 Ain_hi[RPB][AS];   // L1 input (t-folded), hi part
    __shared__ _Float16 Ain_lo[RPB][AS];   // L1 input, lo part (fp32-exact split)
    __shared__ _Float16 h1b[2][RPB][HS];   // layer-1 out per mlp
    __shared__ _Float16 h2b[2][RPB][HS];   // layer-2 out per mlp
    __shared__ _Float16 zb[2][RPB][AS];    // z stash (f16) for MFMA readout
    __shared__ float    bias1t[2 * MW];    // per-step L1 bias incl. t * W0row0
    __shared__ float    tsS[T_STEPS];

    const int tid  = threadIdx.x;
    const int lane = tid & 63;
    const int wid  = tid >> 6;     // 0..7
    const int l15  = lane & 15;
    const int quad = lane >> 4;
    const int mlp  = wid >> 2;     // phase-1/2 role: 0 = drift, 1 = diff
    const int nq   = wid & 3;      // neuron quarter (32-col slice of L1/L2)
    const int rowbase = blockIdx.x * RPB;

    for (int i = tid; i < T_STEPS; i += NTH) tsS[i] = ts[i];

    const float t0   = ts[0];
    const float dt   = ts[1] - t0;
    const float sqdt = sqrtf(dt);

    // ---------------- static weight fragments in VGPRs ----------------
    const float* W0 = mlp ? gW0 : dW0;   // (65,128); row 0 = t weights
    const float* W1 = mlp ? gW1 : dW1;   // (128,128)

    half8 bw1[2][2], bw2[4][2];
    #pragma unroll
    for (int kt = 0; kt < 2; ++kt)
        #pragma unroll
        for (int nt = 0; nt < 2; ++nt) {
            half8 v;
            #pragma unroll
            for (int j = 0; j < 8; ++j) {
                const int k = kt * 32 + quad * 8 + j;
                const int n = nq * 32 + nt * 16 + l15;
                v[j] = (_Float16)W0[(1 + k) * MW + n];
            }
            bw1[kt][nt] = v;
        }
    #pragma unroll
    for (int kt = 0; kt < 4; ++kt)
        #pragma unroll
        for (int nt = 0; nt < 2; ++nt) {
            half8 v;
            #pragma unroll
            for (int j = 0; j < 8; ++j) {
                const int k = kt * 32 + quad * 8 + j;
                const int n = nq * 32 + nt * 16 + l15;
                v[j] = (_Float16)W1[k * MW + n];
            }
            bw2[kt][nt] = v;
        }

    float b2v[2];
    {
        const float* b1p = mlp ? gb1 : db1;
        #pragma unroll
        for (int nt = 0; nt < 2; ++nt) b2v[nt] = b1p[nq * 32 + nt * 16 + l15];
    }

    // ---------------- phase-3 role state ----------------
    // waves 0..3: state waves. wave nq owns cols ucol = nq*16+l15, rows quad*4+i.
    const int ucol = nq * 16 + l15;
    const int urow = quad * 4;

    half8 bw3f[4], bw3g[4];          // Wo fragments for BOTH mlps (wid<4 only)
    float b3f = 0.0f, b3g = 0.0f;
    float z[4], zh[4], fold[4], gold[4], dwr[4], dn[4];
    if (wid < 4) {
        #pragma unroll
        for (int kt = 0; kt < 4; ++kt) {
            half8 vf, vg;
            #pragma unroll
            for (int j = 0; j < 8; ++j) {
                const int k = kt * 32 + quad * 8 + j;
                vf[j] = (_Float16)dWo[k * HID + ucol];
                vg[j] = (_Float16)gWo[k * HID + ucol];
            }
            bw3f[kt] = vf;
            bw3g[kt] = vg;
        }
        b3f = dbo[ucol];
        b3g = gbo[ucol];
        #pragma unroll
        for (int i = 0; i < 4; ++i) {
            z[i] = 1.0f; zh[i] = 1.0f; dwr[i] = 0.0f;
            dn[i] = dW[(size_t)(rowbase + urow + i) * HID + ucol];   // dW[0]
            Ain_hi[urow + i][ucol] = (_Float16)1.0f;                 // x0 = ones
            Ain_lo[urow + i][ucol] = (_Float16)0.0f;
        }
    }

    // readout fragments (wave 4)
    half8 brd[2];
    float rbv = 0.0f;
    int   ocol = 0;
    if (wid == 4) {
        #pragma unroll
        for (int kt = 0; kt < 2; ++kt) {
            half8 v;
            #pragma unroll
            for (int j = 0; j < 8; ++j) {
                const int k = kt * 32 + quad * 8 + j;
                v[j] = (l15 < 8) ? (_Float16)rW[k * DOUT + l15] : (_Float16)0.0f;
            }
            brd[kt] = v;
        }
        rbv  = (l15 < 8) ? rb[l15] : 0.0f;
        ocol = (l15 == 8) ? 0 : (l15 + 1);
    }

    // t-folded L1 bias owned by waves 4..7 (256 threads cover 2*MW slots)
    float b0s = 0.0f, w0s = 0.0f;
    if (tid >= 256) {
        const int idx = tid - 256;
        b0s = (idx < MW ? db0 : gb0)[idx & (MW - 1)];
        w0s = (idx < MW ? dW0 : gW0)[idx & (MW - 1)];  // W0 row 0
        bias1t[idx] = b0s + t0 * w0s;
    }
    __syncthreads();

    for (int n = 1; n <= T_STEPS; ++n) {
        // ================= Phase 1: Layer 1, 64 -> 128 (split-A) ===========
        {
            const int koff = quad * 8;
            half8 ah[2], al[2];
            #pragma unroll
            for (int kt = 0; kt < 2; ++kt) {
                ah[kt] = *(const half8*)&Ain_hi[l15][kt * 32 + koff];
                al[kt] = *(const half8*)&Ain_lo[l15][kt * 32 + koff];
            }
            f32x4 acc[2];
            #pragma unroll
            for (int nt = 0; nt < 2; ++nt) {
                const float b = bias1t[mlp * MW + nq * 32 + nt * 16 + l15];
                acc[nt] = (f32x4){b, b, b, b};
            }
            #pragma unroll
            for (int nt = 0; nt < 2; ++nt)
                #pragma unroll
                for (int kt = 0; kt < 2; ++kt) {
                    acc[nt] = MFMA(ah[kt], bw1[kt][nt], acc[nt]);
                    acc[nt] = MFMA(al[kt], bw1[kt][nt], acc[nt]);
                }
            #pragma unroll
            for (int nt = 0; nt < 2; ++nt)
                #pragma unroll
                for (int i2 = 0; i2 < 4; ++i2) {
                    const float v = lipswish(acc[nt][i2]);
                    h1b[mlp][quad * 4 + i2][nq * 32 + nt * 16 + l15] = (_Float16)v;
                }
        }
        __syncthreads();

        // ================= Phase 2: Layer 2, 128 -> 128 =================
        {
            half8 a[4];
            #pragma unroll
            for (int kt = 0; kt < 4; ++kt)
                a[kt] = *(const half8*)&h1b[mlp][l15][kt * 32 + quad * 8];
            f32x4 acc[2];
            #pragma unroll
            for (int nt = 0; nt < 2; ++nt)
                acc[nt] = (f32x4){b2v[nt], b2v[nt], b2v[nt], b2v[nt]};
            #pragma unroll
            for (int nt = 0; nt < 2; ++nt)
                #pragma unroll
                for (int kt = 0; kt < 4; ++kt)
                    acc[nt] = MFMA(a[kt], bw2[kt][nt], acc[nt]);
            #pragma unroll
            for (int nt = 0; nt < 2; ++nt)
                #pragma unroll
                for (int i2 = 0; i2 < 4; ++i2) {
                    const float v = lipswish(acc[nt][i2]);
                    h2b[mlp][quad * 4 + i2][nq * 32 + nt * 16 + l15] = (_Float16)v;
                }
        }
        __syncthreads();

        // ===== Phase 3: L3 f&g paired (waves 0-3) + in-register update;
        //                readout + bias refresh (waves 4-7) =====
        if (wid < 4) {
            half8 a[4];
            #pragma unroll
            for (int kt = 0; kt < 4; ++kt)
                a[kt] = *(const half8*)&h2b[0][l15][kt * 32 + quad * 8];
            f32x4 accF = (f32x4){b3f, b3f, b3f, b3f};
            #pragma unroll
            for (int kt = 0; kt < 4; ++kt)
                accF = MFMA(a[kt], bw3f[kt], accF);
            #pragma unroll
            for (int kt = 0; kt < 4; ++kt)
                a[kt] = *(const half8*)&h2b[1][l15][kt * 32 + quad * 8];
            f32x4 accG = (f32x4){b3g, b3g, b3g, b3g};
            #pragma unroll
            for (int kt = 0; kt < 4; ++kt)
                accG = MFMA(a[kt], bw3g[kt], accG);

            const int p = n & 1;
            const int np = (n < T_STEPS - 2) ? n : (T_STEPS - 2);
            #pragma unroll
            for (int i = 0; i < 4; ++i) {
                const float fn = fast_tanh(accF[i]);
                const float gn = fast_tanh(accG[i]);
                if (n > 1)
                    z[i] += 0.5f * (fold[i] + fn) * dt + 0.5f * (gold[i] + gn) * dwr[i];
                zb[p][urow + i][ucol] = (_Float16)z[i];
                if (n < T_STEPS) {
                    dwr[i] = dn[i] * sqdt;
                    dn[i]  = dW[(size_t)np * (BATCH * HID)
                                + (size_t)(rowbase + urow + i) * HID + ucol];
                    zh[i]  = 2.0f * z[i] - zh[i] + fn * dt + gn * dwr[i];
                    const _Float16 hi = (_Float16)zh[i];
                    Ain_hi[urow + i][ucol] = hi;
                    Ain_lo[urow + i][ucol] = (_Float16)(zh[i] - (float)hi);
                }
                fold[i] = fn; gold[i] = gn;
            }
        } else {
            // readout of z_{n-2} via MFMA (wave 4); zb[(n-1)&1] last written
            // at step n-1 (barrier-separated); update writes zb[n&1] - no race.
            if (wid == 4 && n >= 2) {
                const int koff = quad * 8, q = (n - 1) & 1, s = n - 2;
                half8 a0 = *(const half8*)&zb[q][l15][koff];
                half8 a1 = *(const half8*)&zb[q][l15][32 + koff];
                f32x4 racc = (f32x4){rbv, rbv, rbv, rbv};
                racc = MFMA(a0, brd[0], racc);
                racc = MFMA(a1, brd[1], racc);
                if (l15 < 9) {
                    const float tv = tsS[s];
                    #pragma unroll
                    for (int i2 = 0; i2 < 4; ++i2) {
                        const int r = quad * 4 + i2;
                        out[(size_t)(rowbase + r) * (T_STEPS * 9) + s * 9 + ocol]
                            = (l15 < 8) ? racc[i2] : tv;
                    }
                }
            }
            if (n < T_STEPS) bias1t[tid - 256] = b0s + tsS[n] * w0s;
        }
        __syncthreads();
    }

    // ---- epilogue: readout of z_255 (stashed in zb[0] at step 256) ----
    if (wid == 4) {
        const int koff = quad * 8, s = T_STEPS - 1;
        half8 a0 = *(const half8*)&zb[0][l15][koff];
        half8 a1 = *(const half8*)&zb[0][l15][32 + koff];
        f32x4 racc = (f32x4){rbv, rbv, rbv, rbv};
        racc = MFMA(a0, brd[0], racc);
        racc = MFMA(a1, brd[1], racc);
        if (l15 < 9) {
            const float tv = tsS[s];
            #pragma unroll
            for (int i2 = 0; i2 < 4; ++i2) {
                const int r = quad * 4 + i2;
                out[(size_t)(rowbase + r) * (T_STEPS * 9) + s * 9 + ocol]
                    = (l15 < 8) ? racc[i2] : tv;
            }
        }
    }
}

extern "C" void kernel_launch(void* const* d_in, const int* in_sizes, int n_in,
                              void* d_out, int out_size, void* d_ws, size_t ws_size,
                              hipStream_t stream) {
    const float* ts  = (const float*)d_in[0];
    const float* dW  = (const float*)d_in[2];
    const float* dW0 = (const float*)d_in[3];
    const float* db0 = (const float*)d_in[4];
    const float* dW1 = (const float*)d_in[5];
    const float* db1 = (const float*)d_in[6];
    const float* dWo = (const float*)d_in[7];
    const float* dbo = (const float*)d_in[8];
    const float* gW0 = (const float*)d_in[9];
    const float* gb0 = (const float*)d_in[10];
    const float* gW1 = (const float*)d_in[11];
    const float* gb1 = (const float*)d_in[12];
    const float* gWo = (const float*)d_in[13];
    const float* gbo = (const float*)d_in[14];
    const float* rW  = (const float*)d_in[15];
    const float* rb  = (const float*)d_in[16];
    float* out = (float*)d_out;

    sde_kernel<<<dim3(BATCH / RPB), dim3(NTH), 0, stream>>>(
        ts, dW, dW0, db0, dW1, db1, dWo, dbo,
        gW0, gb0, gW1, gb1, gWo, gbo, rW, rb, out);
}